// Round 5
// baseline (102.089 us; speedup 1.0000x reference)
//
#include <hip/hip_runtime.h>
#include <math.h>

// Chamfer distance: B=16, N=M=2048, D=3, fp32 — single fused kernel.
// Grid 512 (2/CU): block = (combo, slice-pair); each 128-thread half-block
//   scans one 64-pt opposing slice (SoA LDS, broadcast ds_read_b128) for
//   2048 src points (16/thread), packed fp32 fma + min3 -> 2 VALU/pair.
//   Partial minima of s = |y|^2 - 2 x.y written coalesced to d_ws.
// Ticket level 1: last of each combo's 16 blocks min-reduces its 32 slices
//   (coalesced float4 L2 reads), adds |x|^2, block-sums -> combosum[combo].
// Ticket level 2: last of the 32 reducers sums combosum -> out[0].
// Counters zeroed by a 132-B hipMemsetAsync before the kernel.

typedef float v2f __attribute__((ext_vector_type(2)));

#define NPTS    2048
#define NCOMBO  32           // 2 dirs x 16 batches
#define KSLICE  32
#define SLICE   64           // NPTS / KSLICE
#define SPT     16           // src points per thread (stage 1)

__device__ __forceinline__ v2f pkfma(v2f a, v2f b, v2f c) {
#if __has_builtin(__builtin_elementwise_fma)
    return __builtin_elementwise_fma(a, b, c);
#else
    v2f d; d.x = fmaf(a.x, b.x, c.x); d.y = fmaf(a.y, b.y, c.y); return d;
#endif
}

__device__ __forceinline__ float4 fmin4(float4 a, float4 b) {
    return make_float4(fminf(a.x, b.x), fminf(a.y, b.y),
                       fminf(a.z, b.z), fminf(a.w, b.w));
}

__global__ __launch_bounds__(256, 2) void chamfer_fused(
    const float* __restrict__ preds,
    const float* __restrict__ tgts,
    float* __restrict__ partial,
    float* __restrict__ combosum,
    int* __restrict__ ccount,      // [NCOMBO], zeroed
    int* __restrict__ gcount,      // [1], zeroed
    float* __restrict__ out)
{
    __shared__ __align__(16) float qx[2][SLICE];
    __shared__ __align__(16) float qy[2][SLICE];
    __shared__ __align__(16) float qz[2][SLICE];
    __shared__ __align__(16) float qw[2][SLICE];
    __shared__ float wsum[4];
    __shared__ bool  amLast, amLast2;

    const int bid   = blockIdx.x;        // 0..511
    const int combo = bid & (NCOMBO - 1);
    const int spair = bid >> 5;          // 0..15
    const int dir   = combo >> 4;
    const int b     = combo & 15;

    const int sb    = threadIdx.x >> 7;  // half-block 0/1
    const int tt    = threadIdx.x & 127;
    const int slice = spair * 2 + sb;

    const float* src = (dir ? tgts : preds) + (size_t)b * NPTS * 3;
    const float* opp = (dir ? preds : tgts) + (size_t)b * NPTS * 3;

    // ---- Stage 1: partial minima over this block's two opposing slices ----
    if (tt < SLICE) {
        const int jj = slice * SLICE + tt;
        const float y0 = opp[3 * jj + 0];
        const float y1 = opp[3 * jj + 1];
        const float y2 = opp[3 * jj + 2];
        qx[sb][tt] = y0;
        qy[sb][tt] = y1;
        qz[sb][tt] = y2;
        qw[sb][tt] = y0 * y0 + y1 * y1 + y2 * y2;
    }

    v2f nn0[SPT], nn1[SPT], nn2[SPT];
    float m[SPT];
    #pragma unroll
    for (int k = 0; k < SPT; k++) {
        const int i = tt + 128 * k;
        const float a0 = -2.0f * src[3 * i + 0];
        const float a1 = -2.0f * src[3 * i + 1];
        const float a2 = -2.0f * src[3 * i + 2];
        nn0[k] = (v2f){a0, a0};
        nn1[k] = (v2f){a1, a1};
        nn2[k] = (v2f){a2, a2};
        m[k]   = INFINITY;
    }
    __syncthreads();

    #pragma unroll 2
    for (int jg = 0; jg < SLICE / 4; jg++) {
        const float4 X = *(const float4*)&qx[sb][4 * jg];
        const float4 Y = *(const float4*)&qy[sb][4 * jg];
        const float4 Z = *(const float4*)&qz[sb][4 * jg];
        const float4 W = *(const float4*)&qw[sb][4 * jg];
        const v2f Xa = {X.x, X.y}, Xb = {X.z, X.w};
        const v2f Ya = {Y.x, Y.y}, Yb = {Y.z, Y.w};
        const v2f Za = {Z.x, Z.y}, Zb = {Z.z, Z.w};
        const v2f Wa = {W.x, W.y}, Wb = {W.z, W.w};
        #pragma unroll
        for (int k = 0; k < SPT; k++) {
            const v2f sa = pkfma(nn0[k], Xa, pkfma(nn1[k], Ya, pkfma(nn2[k], Za, Wa)));
            m[k] = fminf(fminf(m[k], sa.x), sa.y);
            const v2f sb2 = pkfma(nn0[k], Xb, pkfma(nn1[k], Yb, pkfma(nn2[k], Zb, Wb)));
            m[k] = fminf(fminf(m[k], sb2.x), sb2.y);
        }
    }

    float* pp = partial + ((size_t)combo * KSLICE + slice) * NPTS;
    #pragma unroll
    for (int k = 0; k < SPT; k++)
        pp[tt + 128 * k] = m[k];

    // ---- Ticket level 1: last block of this combo reduces its 32 slices ----
    __syncthreads();
    if (threadIdx.x == 0) {
        __threadfence();   // release: partials visible device-wide
        const int old = __hip_atomic_fetch_add(&ccount[combo], 1,
                            __ATOMIC_ACQ_REL, __HIP_MEMORY_SCOPE_AGENT);
        amLast = (old == 15);
    }
    __syncthreads();
    if (!amLast) return;
    __threadfence();       // acquire: see all 16 blocks' partials

    const float* base = partial + (size_t)combo * KSLICE * NPTS;
    const int t = threadIdx.x;
    // Group A: points 4t..4t+3 ; Group B: points 1024+4t..1024+4t+3
    float4 mnA = make_float4(INFINITY, INFINITY, INFINITY, INFINITY);
    float4 mnB = mnA;
    #pragma unroll 4
    for (int s = 0; s < KSLICE; s++) {
        mnA = fmin4(mnA, *(const float4*)&base[(size_t)s * NPTS + 4 * t]);
        mnB = fmin4(mnB, *(const float4*)&base[(size_t)s * NPTS + 1024 + 4 * t]);
    }
    // |x|^2 for the 8 points (48t is 16B-aligned)
    const float4 rA0 = *(const float4*)&src[12 * t + 0];
    const float4 rA1 = *(const float4*)&src[12 * t + 4];
    const float4 rA2 = *(const float4*)&src[12 * t + 8];
    const float4 rB0 = *(const float4*)&src[3072 + 12 * t + 0];
    const float4 rB1 = *(const float4*)&src[3072 + 12 * t + 4];
    const float4 rB2 = *(const float4*)&src[3072 + 12 * t + 8];
    float val =
        (fmaf(rA0.x, rA0.x, fmaf(rA0.y, rA0.y, rA0.z * rA0.z)) + mnA.x) +
        (fmaf(rA0.w, rA0.w, fmaf(rA1.x, rA1.x, rA1.y * rA1.y)) + mnA.y) +
        (fmaf(rA1.z, rA1.z, fmaf(rA1.w, rA1.w, rA2.x * rA2.x)) + mnA.z) +
        (fmaf(rA2.y, rA2.y, fmaf(rA2.z, rA2.z, rA2.w * rA2.w)) + mnA.w) +
        (fmaf(rB0.x, rB0.x, fmaf(rB0.y, rB0.y, rB0.z * rB0.z)) + mnB.x) +
        (fmaf(rB0.w, rB0.w, fmaf(rB1.x, rB1.x, rB1.y * rB1.y)) + mnB.y) +
        (fmaf(rB1.z, rB1.z, fmaf(rB1.w, rB1.w, rB2.x * rB2.x)) + mnB.z) +
        (fmaf(rB2.y, rB2.y, fmaf(rB2.z, rB2.z, rB2.w * rB2.w)) + mnB.w);

    #pragma unroll
    for (int off = 32; off > 0; off >>= 1)
        val += __shfl_down(val, off, 64);
    const int lane = threadIdx.x & 63;
    const int wid  = threadIdx.x >> 6;
    if (lane == 0) wsum[wid] = val;
    __syncthreads();

    // ---- Ticket level 2: last combo-reducer sums the 32 combo sums ----
    if (threadIdx.x == 0) {
        const float bsum = wsum[0] + wsum[1] + wsum[2] + wsum[3];
        __hip_atomic_store(&combosum[combo], bsum,
                           __ATOMIC_RELAXED, __HIP_MEMORY_SCOPE_AGENT);
        __threadfence();
        const int old = __hip_atomic_fetch_add(gcount, 1,
                            __ATOMIC_ACQ_REL, __HIP_MEMORY_SCOPE_AGENT);
        amLast2 = (old == NCOMBO - 1);
    }
    __syncthreads();
    if (!amLast2) return;
    __threadfence();

    if (threadIdx.x < 64) {
        float v = (threadIdx.x < NCOMBO)
            ? __hip_atomic_load(&combosum[threadIdx.x],
                                __ATOMIC_RELAXED, __HIP_MEMORY_SCOPE_AGENT)
            : 0.0f;
        #pragma unroll
        for (int off = 32; off > 0; off >>= 1)
            v += __shfl_down(v, off, 64);
        if (threadIdx.x == 0) out[0] = v;
    }
}

extern "C" void kernel_launch(void* const* d_in, const int* in_sizes, int n_in,
                              void* d_out, int out_size, void* d_ws, size_t ws_size,
                              hipStream_t stream) {
    const float* preds = (const float*)d_in[0];
    const float* tgts  = (const float*)d_in[1];
    float* out      = (float*)d_out;
    float* partial  = (float*)d_ws;                              // 8 MB
    float* combosum = partial + (size_t)NCOMBO * KSLICE * NPTS;  // 32 floats
    int*   ccount   = (int*)(combosum + NCOMBO);                 // 32 ints
    int*   gcount   = ccount + NCOMBO;                           // 1 int

    hipMemsetAsync(ccount, 0, (NCOMBO + 1) * sizeof(int), stream);
    chamfer_fused<<<NCOMBO * (KSLICE / 2), 256, 0, stream>>>(
        preds, tgts, partial, combosum, ccount, gcount, out);
}

// Round 6
// 71.123 us; speedup vs baseline: 1.4354x; 1.4354x over previous
//
#include <hip/hip_runtime.h>
#include <math.h>

// Chamfer distance: B=16, N=M=2048, D=3, fp32. Two kernels, two graph nodes.
// Stage 1 (512 blocks, 2/CU): block = (combo, slice); scans a 128-pt opposing
//   slice (SoA LDS, broadcast ds_read_b128) for all 2048 src pts (8/thread),
//   packed fp32 fma + min3 -> 2 VALU ops/pair. Partial minima of
//   s = |y|^2 - 2 x.y -> d_ws (4 MB, coalesced). Block 0 zeroes out[0]
//   (stream order makes it visible before stage 2's atomics).
// Stage 2 (256 blocks): min over 16 slices, add |x|^2, block-sum, one
//   atomicAdd per block. No tickets, no fences (R3/R5 showed agent-scope
//   fence/invalidate storms + weak tails cost far more than a dispatch).

typedef float v2f __attribute__((ext_vector_type(2)));

#define NPTS    2048
#define NCOMBO  32           // 2 dirs x 16 batches
#define KSLICE  16
#define SLICE   128          // NPTS / KSLICE
#define SPT     8            // src points per thread (stage 1)

__device__ __forceinline__ v2f pkfma(v2f a, v2f b, v2f c) {
#if __has_builtin(__builtin_elementwise_fma)
    return __builtin_elementwise_fma(a, b, c);
#else
    v2f d; d.x = fmaf(a.x, b.x, c.x); d.y = fmaf(a.y, b.y, c.y); return d;
#endif
}

__global__ __launch_bounds__(256, 2) void chamfer_partial(
    const float* __restrict__ preds,
    const float* __restrict__ tgts,
    float* __restrict__ partial,
    float* __restrict__ out)
{
    __shared__ __align__(16) float qx[SLICE];
    __shared__ __align__(16) float qy[SLICE];
    __shared__ __align__(16) float qz[SLICE];
    __shared__ __align__(16) float qw[SLICE];

    const int bid   = blockIdx.x;        // 0..511
    const int combo = bid & (NCOMBO - 1);
    const int slice = bid >> 5;          // 0..15
    const int dir   = combo >> 4;
    const int b     = combo & 15;

    if (bid == 0 && threadIdx.x == 0) out[0] = 0.0f;   // done before stage 2

    const float* src = (dir ? tgts : preds) + (size_t)b * NPTS * 3;
    const float* opp = (dir ? preds : tgts) + (size_t)b * NPTS * 3;

    // Stage opposing slice (SoA, |y|^2 in qw)
    if (threadIdx.x < SLICE) {
        const int jj = slice * SLICE + threadIdx.x;
        const float y0 = opp[3 * jj + 0];
        const float y1 = opp[3 * jj + 1];
        const float y2 = opp[3 * jj + 2];
        qx[threadIdx.x] = y0;
        qy[threadIdx.x] = y1;
        qz[threadIdx.x] = y2;
        qw[threadIdx.x] = y0 * y0 + y1 * y1 + y2 * y2;
    }

    // 8 src points per thread; nn = -2*x duplicated for packed math
    v2f nn0[SPT], nn1[SPT], nn2[SPT];
    float m[SPT];
    #pragma unroll
    for (int k = 0; k < SPT; k++) {
        const int i = threadIdx.x + 256 * k;
        const float a0 = -2.0f * src[3 * i + 0];
        const float a1 = -2.0f * src[3 * i + 1];
        const float a2 = -2.0f * src[3 * i + 2];
        nn0[k] = (v2f){a0, a0};
        nn1[k] = (v2f){a1, a1};
        nn2[k] = (v2f){a2, a2};
        m[k]   = INFINITY;
    }
    __syncthreads();

    #pragma unroll 2
    for (int jg = 0; jg < SLICE / 4; jg++) {
        const float4 X = *(const float4*)&qx[4 * jg];
        const float4 Y = *(const float4*)&qy[4 * jg];
        const float4 Z = *(const float4*)&qz[4 * jg];
        const float4 W = *(const float4*)&qw[4 * jg];
        const v2f Xa = {X.x, X.y}, Xb = {X.z, X.w};
        const v2f Ya = {Y.x, Y.y}, Yb = {Y.z, Y.w};
        const v2f Za = {Z.x, Z.y}, Zb = {Z.z, Z.w};
        const v2f Wa = {W.x, W.y}, Wb = {W.z, W.w};
        #pragma unroll
        for (int k = 0; k < SPT; k++) {
            const v2f sa = pkfma(nn0[k], Xa, pkfma(nn1[k], Ya, pkfma(nn2[k], Za, Wa)));
            m[k] = fminf(fminf(m[k], sa.x), sa.y);        // v_min3_f32
            const v2f sb = pkfma(nn0[k], Xb, pkfma(nn1[k], Yb, pkfma(nn2[k], Zb, Wb)));
            m[k] = fminf(fminf(m[k], sb.x), sb.y);        // v_min3_f32
        }
    }

    float* pp = partial + ((size_t)combo * KSLICE + slice) * NPTS;
    #pragma unroll
    for (int k = 0; k < SPT; k++)
        pp[threadIdx.x + 256 * k] = m[k];
}

__global__ __launch_bounds__(256) void chamfer_reduce(
    const float* __restrict__ preds,
    const float* __restrict__ tgts,
    const float* __restrict__ partial,
    float* __restrict__ out)
{
    __shared__ float wsum[4];

    const int idx   = blockIdx.x * 256 + threadIdx.x;   // 0..65535
    const int combo = idx >> 11;                        // uniform per block
    const int i     = idx & (NPTS - 1);
    const int dir   = combo >> 4;
    const int b     = combo & 15;

    const float* src = (dir ? tgts : preds) + (size_t)b * NPTS * 3;
    const float x0 = src[3 * i + 0];
    const float x1 = src[3 * i + 1];
    const float x2 = src[3 * i + 2];
    const float xx = x0 * x0 + x1 * x1 + x2 * x2;

    const float* pp = partial + (size_t)combo * KSLICE * NPTS + i;
    float mn = pp[0];
    #pragma unroll
    for (int s = 1; s < KSLICE; s++)
        mn = fminf(mn, pp[(size_t)s * NPTS]);

    float val = xx + mn;

    #pragma unroll
    for (int off = 32; off > 0; off >>= 1)
        val += __shfl_down(val, off, 64);

    const int lane = threadIdx.x & 63;
    const int wid  = threadIdx.x >> 6;
    if (lane == 0) wsum[wid] = val;
    __syncthreads();
    if (threadIdx.x == 0)
        atomicAdd(out, wsum[0] + wsum[1] + wsum[2] + wsum[3]);
}

extern "C" void kernel_launch(void* const* d_in, const int* in_sizes, int n_in,
                              void* d_out, int out_size, void* d_ws, size_t ws_size,
                              hipStream_t stream) {
    const float* preds = (const float*)d_in[0];
    const float* tgts  = (const float*)d_in[1];
    float* out     = (float*)d_out;
    float* partial = (float*)d_ws;   // 32 combos x 16 slices x 2048 = 4 MB

    chamfer_partial<<<NCOMBO * KSLICE, 256, 0, stream>>>(preds, tgts, partial, out);
    chamfer_reduce<<<(2 * 16 * NPTS) / 256, 256, 0, stream>>>(preds, tgts, partial, out);
}